// Round 3
// baseline (371.966 us; speedup 1.0000x reference)
//
#include <hip/hip_runtime.h>
#include <hip/hip_bf16.h>

#define BATCH 16
#define CIN 64
#define COUT 64
#define HH 160
#define WW 160

typedef __attribute__((ext_vector_type(8))) __bf16 bf16x8;
typedef __attribute__((ext_vector_type(4))) float f32x4;

// ---------------------------------------------------------------------------
// Weight: w (O, C, 3, 3) fp32 -> wb[tap][o][c] bf16  (tap = ky*3+kx)
// ---------------------------------------------------------------------------
__global__ __launch_bounds__(256) void wcvt(const float* __restrict__ w,
                                            unsigned short* __restrict__ wb) {
  int e = blockIdx.x * 256 + threadIdx.x;
  if (e >= 9 * 64 * 64) return;
  int tap = e >> 12;  // / 4096
  int o = (e >> 6) & 63;
  int c = e & 63;
  float v = w[((size_t)(o * 64 + c)) * 9 + tap];
  __hip_bfloat16 h = __float2bfloat16(v);
  wb[e] = *reinterpret_cast<unsigned short*>(&h);
}

// ---------------------------------------------------------------------------
// Fused shift + implicit-GEMM conv. Block = (b, 16x16 spatial tile) x 64 och.
// Staging reads NCHW fp32 x directly, applying the per-channel (dy,dx) shift
// and bf16 conversion on the way into LDS — the xs intermediate (54 MB write
// + 54 MB read + a whole latency-bound pass) is eliminated.
//
// Staging map: task s = (c, pc); thread loads 18 rows of its (channel,col)
// with that channel's shift applied, zero outside the valid range.
// 18 consecutive lanes (same c, pc=0..17) read 72 B contiguous per row.
//
// LDS: 18x18 pixels x 64ch bf16, pixel stride padded to 72 (A-reads stay
// conflict-free as in R1/R2). MFMA loop + epilogue identical to R2:
// mfma_f32_16x16x32_bf16, A[m=lane&15][k=q*8+j], B[k][n=lane&15],
// D[row=q*4+r][col=lane&15]  (m89/m91-verified layout).
// ---------------------------------------------------------------------------
__global__ __launch_bounds__(256, 3) void conv_fused(const float* __restrict__ x,
                                                     const unsigned short* __restrict__ wb,
                                                     float* __restrict__ out) {
  __shared__ unsigned short lds_in[324 * 72];  // 46,656 B

  int tj = blockIdx.x, ti = blockIdx.y, b = blockIdx.z;
  int tid = threadIdx.x;
  int y0 = ti * 16, x0 = tj * 16;

  // ---- stage 18x18x64 halo tile from x (fp32 NCHW), shift folded in ----
  for (int s = tid; s < 1152; s += 256) {
    int c = s / 18;
    int pc = s - c * 18;
    int cm = c % 5;
    int dx = (cm == 1) ? 1 : ((cm == 3) ? -1 : 0);
    int dy = (cm == 2) ? 1 : ((cm == 4) ? -1 : 0);
    int cc = x0 + pc - 1 - dx;  // source col (0..159 valid)
    bool cok = (cc >= 0 && cc < WW);
    const float* plane = x + (size_t)(b * CIN + c) * (HH * WW);
    int ry0 = y0 - 1 - dy;
#pragma unroll
    for (int pr = 0; pr < 18; ++pr) {
      int ry = ry0 + pr;  // source row (0..159 valid)
      float v = 0.f;
      if (cok && ry >= 0 && ry < HH) v = plane[ry * WW + cc];
      __hip_bfloat16 h = __float2bfloat16(v);
      lds_in[(pr * 18 + pc) * 72 + c] = *reinterpret_cast<unsigned short*>(&h);
    }
  }
  __syncthreads();

  int wv = tid >> 6;  // wave 0..3 -> li in [4w, 4w+4)
  int lane = tid & 63;
  int l15 = lane & 15;
  int q = lane >> 4;

  f32x4 acc[4][4];
#pragma unroll
  for (int a = 0; a < 4; ++a)
#pragma unroll
    for (int bb = 0; bb < 4; ++bb) acc[a][bb] = (f32x4){0.f, 0.f, 0.f, 0.f};

  for (int tap = 0; tap < 9; ++tap) {
    int ky = tap / 3, kx = tap - ky * 3;
#pragma unroll
    for (int ch = 0; ch < 2; ++ch) {
      int c0 = ch * 32;
      bf16x8 A[4], Bf[4];
#pragma unroll
      for (int mt = 0; mt < 4; ++mt) {
        int li = 4 * wv + mt;
        A[mt] = *reinterpret_cast<const bf16x8*>(
            &lds_in[((li + ky) * 18 + (l15 + kx)) * 72 + c0 + q * 8]);
      }
#pragma unroll
      for (int nt = 0; nt < 4; ++nt) {
        Bf[nt] = *reinterpret_cast<const bf16x8*>(
            wb + ((size_t)tap * 64 + (size_t)(nt * 16 + l15)) * 64 + c0 + q * 8);
      }
#pragma unroll
      for (int mt = 0; mt < 4; ++mt)
#pragma unroll
        for (int nt = 0; nt < 4; ++nt)
          acc[mt][nt] = __builtin_amdgcn_mfma_f32_16x16x32_bf16(A[mt], Bf[nt], acc[mt][nt], 0, 0, 0);
    }
  }

  // ---- epilogue: D[row=q*4+r][col=l15] ----
#pragma unroll
  for (int mt = 0; mt < 4; ++mt) {
    int i = y0 + 4 * wv + mt;
#pragma unroll
    for (int nt = 0; nt < 4; ++nt) {
      int o = nt * 16 + l15;
      size_t addr = (((size_t)(b * COUT + o) * HH) + (size_t)i) * WW + (size_t)(x0 + q * 4);
      *reinterpret_cast<f32x4*>(out + addr) = acc[mt][nt];
    }
  }
}

extern "C" void kernel_launch(void* const* d_in, const int* in_sizes, int n_in,
                              void* d_out, int out_size, void* d_ws, size_t ws_size,
                              hipStream_t stream) {
  const float* x = (const float*)d_in[0];
  const float* w = (const float*)d_in[1];
  float* out = (float*)d_out;

  unsigned short* wb = (unsigned short*)d_ws;  // 9*64*64 bf16 = 73,728 B

  hipLaunchKernelGGL(wcvt, dim3(144), dim3(256), 0, stream, w, wb);
  hipLaunchKernelGGL(conv_fused, dim3(10, 10, BATCH), dim3(256), 0, stream, x, wb, out);
}

// Round 4
// 277.003 us; speedup vs baseline: 1.3428x; 1.3428x over previous
//
#include <hip/hip_runtime.h>
#include <hip/hip_bf16.h>

#define BATCH 16
#define CIN 64
#define COUT 64
#define HH 160
#define WW 160
#define HP 162
#define WP 162

typedef __attribute__((ext_vector_type(8))) __bf16 bf16x8;
typedef __attribute__((ext_vector_type(4))) float f32x4;

// ---------------------------------------------------------------------------
// Pass 1 (v3): x (NCHW fp32) -> xs (B, 162, 162, 64) bf16, shift folded in.
// LDS transpose with per-channel dword ROTATION rot(c) = (c&31) + dx(c):
//   - load phase : coalesced f32x4 reads along W; LDS writes at consecutive
//                  positions (conflict-free; 4x b32 to allow non-4-aligned rot)
//   - store phase: lanes along C; bank = (xi-1+(c&31)) mod 32 -> exactly
//                  2 lanes/bank (free per m136), independent of dx by design
//                  (rot absorbs dx). 128 B/wave coalesced bf16 stores.
// ---------------------------------------------------------------------------
__global__ __launch_bounds__(256) void shift_cvt(const float* __restrict__ x,
                                                 unsigned short* __restrict__ xs) {
  __shared__ float lds[64 * 160];  // 40 KB
  int y = blockIdx.x % HP;
  int b = blockIdx.x / HP;
  int tid = threadIdx.x;

  // ---- load: global (coalesced along W) -> LDS rotated ----
#pragma unroll
  for (int it = 0; it < 10; ++it) {
    int idx = it * 256 + tid;  // 0..2559 = 64 ch x 40 f32x4
    int c = idx / 40;
    int j = idx - c * 40;
    int cm = c % 5;
    int dx = (cm == 1) ? 1 : ((cm == 3) ? -1 : 0);
    int dy = (cm == 2) ? 1 : ((cm == 4) ? -1 : 0);
    int yy = y - dy;  // source row (1..160 valid)
    f32x4 v = {0.f, 0.f, 0.f, 0.f};
    if (yy >= 1 && yy <= HH)
      v = *reinterpret_cast<const f32x4*>(
          x + (((size_t)(b * CIN + c)) * HH + (size_t)(yy - 1)) * WW + j * 4);
    int rot = (c & 31) + dx;
    if (rot < 0) rot += 160;
    int p0 = 4 * j + rot;  // < 320
#pragma unroll
    for (int e = 0; e < 4; ++e) {
      int p = p0 + e;
      if (p >= 160) p -= 160;
      lds[c * 160 + p] = v[e];
    }
  }
  __syncthreads();

  // ---- store: LDS -> xs (lanes along C, 128B/wave) ----
  int c = tid & 63;
  int wv = tid >> 6;
  int cm = c % 5;
  int dx = (cm == 1) ? 1 : ((cm == 3) ? -1 : 0);
  int rot = (c & 31) + dx;
  if (rot < 0) rot += 160;
  size_t obase = ((size_t)(b * HP + y) * WP) * CIN + c;
  const float* lrow = &lds[c * 160];
  for (int xi = wv; xi < WP; xi += 4) {
    int xx = xi - dx - 1;  // source x (0..159 valid)
    float v = 0.f;
    if (xx >= 0 && xx < WW) {
      int p = xx + rot;
      if (p >= 160) p -= 160;
      v = lrow[p];
    }
    __hip_bfloat16 h = __float2bfloat16(v);
    xs[obase + (size_t)xi * CIN] = *reinterpret_cast<unsigned short*>(&h);
  }
}

// ---------------------------------------------------------------------------
// Weight: w (O, C, 3, 3) fp32 -> wb[tap][o][c] bf16  (tap = ky*3+kx)
// ---------------------------------------------------------------------------
__global__ __launch_bounds__(256) void wcvt(const float* __restrict__ w,
                                            unsigned short* __restrict__ wb) {
  int e = blockIdx.x * 256 + threadIdx.x;
  if (e >= 9 * 64 * 64) return;
  int tap = e >> 12;
  int o = (e >> 6) & 63;
  int c = e & 63;
  float v = w[((size_t)(o * 64 + c)) * 9 + tap];
  __hip_bfloat16 h = __float2bfloat16(v);
  wb[e] = *reinterpret_cast<unsigned short*>(&h);
}

// ---------------------------------------------------------------------------
// Pass 2 (v3): implicit-GEMM conv, tile = 8 rows x 32 cols x 64 ochans.
//  - full 128 B aligned write granules per (o,row) per block -> L2 merge,
//    WRITE_SIZE -> ideal ~102 MB (was 141 with 64 B half-granules split
//    across XCDs at 16-wide tiles)
//  - tap x ch loop FULLY unrolled: all 72 A-reads become ds_read_b128 with
//    immediate offsets off ONE address register; B loads hoistable by the
//    scheduler across iterations instead of ~200cyc L2 stall per tap
//  - LDS: 10x34 pixels x 64ch bf16, pixel stride 72 shorts (144 B), 48,960 B
// MFMA mapping (m89/m91-verified): m-dim = x-offset (l15), n = ochan,
// D[row=q*4+reg][col=l15] -> x = xbase + q*4 + reg, o = nt*16+l15.
// ---------------------------------------------------------------------------
__global__ __launch_bounds__(256, 3) void conv_mfma(const unsigned short* __restrict__ xs,
                                                    const unsigned short* __restrict__ wb,
                                                    float* __restrict__ out) {
  __shared__ unsigned short lds_in[340 * 72];  // 48,960 B

  int tj = blockIdx.x, ti = blockIdx.y, b = blockIdx.z;
  int tid = threadIdx.x;
  int y0 = ti * 8, x0 = tj * 32;

  // ---- stage 10x34 pixel halo tile (rows y0..y0+9, cols x0..x0+33 padded) --
  const size_t xs_b = (size_t)b * HP * WP * CIN;
#pragma unroll
  for (int k = 0; k < 11; ++k) {
    int u = k * 256 + tid;  // 0..2719 = 340 pixels x 8 chunks
    if (u < 2720) {
      int p = u >> 3, q8 = u & 7;
      int pr = p / 34, pc = p - pr * 34;
      uint4 v = *reinterpret_cast<const uint4*>(
          xs + xs_b + ((size_t)(y0 + pr) * WP + (size_t)(x0 + pc)) * CIN + q8 * 8);
      *reinterpret_cast<uint4*>(&lds_in[p * 72 + q8 * 8]) = v;
    }
  }
  __syncthreads();

  int wv = tid >> 6;
  int lane = tid & 63;
  int l15 = lane & 15;
  int q = lane >> 4;

  // per-lane bases; everything else is compile-time immediates
  const unsigned short* abase = &lds_in[(2 * wv * 34 + l15) * 72 + q * 8];
  const unsigned short* bbase = wb + l15 * 64 + q * 8;

  f32x4 acc[4][4];
#pragma unroll
  for (int a = 0; a < 4; ++a)
#pragma unroll
    for (int bb = 0; bb < 4; ++bb) acc[a][bb] = (f32x4){0.f, 0.f, 0.f, 0.f};

#pragma unroll
  for (int ch = 0; ch < 2; ++ch) {
#pragma unroll
    for (int ky = 0; ky < 3; ++ky) {
#pragma unroll
      for (int kx = 0; kx < 3; ++kx) {
        int tap = ky * 3 + kx;
        bf16x8 Bf[4];
#pragma unroll
        for (int nt = 0; nt < 4; ++nt)
          Bf[nt] = *reinterpret_cast<const bf16x8*>(bbase + tap * 4096 + nt * 1024 + ch * 32);
        bf16x8 A[4];
#pragma unroll
        for (int mt = 0; mt < 4; ++mt)
          A[mt] = *reinterpret_cast<const bf16x8*>(
              abase + ((((mt >> 1) + ky) * 34 + kx + (mt & 1) * 16) * 72 + ch * 32));
#pragma unroll
        for (int mt = 0; mt < 4; ++mt)
#pragma unroll
          for (int nt = 0; nt < 4; ++nt)
            acc[mt][nt] = __builtin_amdgcn_mfma_f32_16x16x32_bf16(A[mt], Bf[nt], acc[mt][nt], 0, 0, 0);
      }
    }
  }

  // ---- epilogue: x = x0 + (mt&1)*16 + q*4 (+reg), row i = y0 + 2wv + (mt>>1)
#pragma unroll
  for (int mt = 0; mt < 4; ++mt) {
    int i = y0 + 2 * wv + (mt >> 1);
    int xo = x0 + (mt & 1) * 16 + q * 4;
#pragma unroll
    for (int nt = 0; nt < 4; ++nt) {
      int o = nt * 16 + l15;
      *reinterpret_cast<f32x4*>(out + ((size_t)(b * COUT + o) * HH + (size_t)i) * WW + xo) =
          acc[mt][nt];
    }
  }
}

extern "C" void kernel_launch(void* const* d_in, const int* in_sizes, int n_in,
                              void* d_out, int out_size, void* d_ws, size_t ws_size,
                              hipStream_t stream) {
  const float* x = (const float*)d_in[0];
  const float* w = (const float*)d_in[1];
  float* out = (float*)d_out;

  unsigned short* xs = (unsigned short*)d_ws;  // 16*162*162*64 bf16 = 53.7 MB
  unsigned short* wb = (unsigned short*)((char*)d_ws + (size_t)BATCH * HP * WP * CIN * 2);

  hipLaunchKernelGGL(shift_cvt, dim3(BATCH * HP), dim3(256), 0, stream, x, xs);
  hipLaunchKernelGGL(wcvt, dim3(144), dim3(256), 0, stream, w, wb);
  hipLaunchKernelGGL(conv_mfma, dim3(5, 20, BATCH), dim3(256), 0, stream, xs, wb, out);
}